// Round 26
// baseline (165.957 us; speedup 1.0000x reference)
//
#include <hip/hip_runtime.h>
#include <hip/hip_bf16.h>

#define BB 16
#define CC 64
#define NN 2048
#define KK 4
#define NPART 4
#define JPER (NN / NPART)
#define NCAND 32
#define RSTRIDE 80  // bf16/row: 64 coords + xx_hi + xx_lo + one(=1.0) + 13 zeros

typedef unsigned short u16;
typedef unsigned int u32;
typedef __attribute__((ext_vector_type(4))) float f32x4;
typedef __attribute__((ext_vector_type(16))) float f32x16;
typedef __attribute__((ext_vector_type(8))) short short8;

__device__ __forceinline__ float bf2f(u16 u) {
    unsigned int x = ((unsigned int)u) << 16;
    float f;
    __builtin_memcpy(&f, &x, 4);
    return f;
}
__device__ __forceinline__ u16 f2bf(float f) {
    __hip_bfloat16 h = __float2bfloat16(f);
    u16 u;
    __builtin_memcpy(&u, &h, 2);
    return u;
}
__device__ __forceinline__ unsigned int pk2(float a, float b) {
    return (unsigned int)f2bf(a) | ((unsigned int)f2bf(b) << 16);
}
__device__ __forceinline__ u32 umx(u32 a, u32 b) { return a > b ? a : b; }
__device__ __forceinline__ u32 umn(u32 a, u32 b) { return a < b ? a : b; }

// K1: transpose x -> xt fp32, xx64 fp64, and xpk (B,N,80) bf16:
// [0..63]=x, [64]=xx_hi, [65]=xx_lo, [66]=1.0, [67..79]=0.
__global__ __launch_bounds__(256) void k_prep(const float* __restrict__ x,
                                              float* __restrict__ xt,
                                              double* __restrict__ xx64,
                                              u16* __restrict__ xpk) {
    int b = blockIdx.y;
    int n = blockIdx.x * 256 + threadIdx.x;
    const float* xb = x + (size_t)b * CC * NN;
    float v[CC];
    float s = 0.f;
    double s64 = 0.0;
#pragma unroll
    for (int c = 0; c < CC; c++) {
        v[c] = xb[(size_t)c * NN + n];
        s = fmaf(v[c], v[c], s);
        s64 += (double)v[c] * (double)v[c];
    }
    float4* dst = (float4*)(xt + ((size_t)b * NN + n) * CC);
#pragma unroll
    for (int q = 0; q < 16; q++) {
        dst[q] = make_float4(v[4 * q], v[4 * q + 1], v[4 * q + 2], v[4 * q + 3]);
    }
    xx64[b * NN + n] = s64;
    u16* dp = xpk + ((size_t)b * NN + n) * RSTRIDE;
#pragma unroll
    for (int q = 0; q < 8; q++) {
        uint4 u;
        u.x = pk2(v[8 * q], v[8 * q + 1]);
        u.y = pk2(v[8 * q + 2], v[8 * q + 3]);
        u.z = pk2(v[8 * q + 4], v[8 * q + 5]);
        u.w = pk2(v[8 * q + 6], v[8 * q + 7]);
        *(uint4*)(dp + q * 8) = u;
    }
    u16 hi = f2bf(s);
    u16 lo = f2bf(s - bf2f(hi));
    uint4 u8;
    u8.x = (unsigned int)hi | ((unsigned int)lo << 16);
    u8.y = 0x00003F80u;  // [66] = bf16(1.0)  (bias column)
    u8.z = 0; u8.w = 0;
    *(uint4*)(dp + 64) = u8;
    uint4 z = {0, 0, 0, 0};
    *(uint4*)(dp + 72) = z;
}

// K1b: pack weights to bf16 fragment-linear layout (for 16x16x32 MLP mfma).
__global__ __launch_bounds__(256) void k_wprep(const float* __restrict__ w1,
                                               const float* __restrict__ w2,
                                               const float* __restrict__ w3,
                                               u16* __restrict__ wb1,
                                               u16* __restrict__ wb2,
                                               u16* __restrict__ wb3) {
    int t = blockIdx.x * 256 + threadIdx.x;
    int stride = gridDim.x * 256;
    for (int idx = t; idx < 64 * 128; idx += stride) {  // w1: 64 out x 128 k
        int o = idx >> 7, k = idx & 127;
        int cb = o >> 4, lr = o & 15, ks = k >> 5, g = (k >> 3) & 3, e = k & 7;
        wb1[((cb * 4 + ks) * 64 + g * 16 + lr) * 8 + e] = f2bf(w1[idx]);
    }
    for (int idx = t; idx < 128 * 192; idx += stride) {  // w2: 128 out x 192 k
        int o = idx / 192, k = idx - o * 192;
        int cb = o >> 4, lr = o & 15, ks = k >> 5, g = (k >> 3) & 3, e = k & 7;
        wb2[((cb * 6 + ks) * 64 + g * 16 + lr) * 8 + e] = f2bf(w2[idx]);
    }
    for (int idx = t; idx < 64 * 64; idx += stride) {  // w3: 64 out x 64 k
        int o = idx >> 6, k = idx & 63;
        int cb = o >> 4, lr = o & 15, ks = k >> 5, g = (k >> 3) & 3, e = k & 7;
        wb3[((cb * 2 + ks) * 64 + g * 16 + lr) * 8 + e] = f2bf(w3[idx]);
    }
}

// K2: swapped-operand MFMA KNN, K=80. acc = dot - xx_j/2 + 128 (>0), so fp32
// bits order as u32. 9-bit j-local index packed into low mantissa bits;
// branchless sorting networks. Top-4 per lane half-stream -> 32 cand/i.
__global__ __launch_bounds__(256) void k_knn3(const u16* __restrict__ xpk,
                                              u16* __restrict__ cand) {
    int ib = blockIdx.x;   // 0..15  (128 i-rows each)
    int part = blockIdx.y; // 0..NPART-1
    int b = blockIdx.z;
    int tid = threadIdx.x;
    int i0 = ib * 128;
    int j00 = part * JPER;

    // Bb: [buf][sub][chunk 0..9][slot=r32^(c&7)][16B]
    __shared__ u16 Bb[2 * 2 * 10 * 32 * 8];  // 20 KB

    int w = tid >> 6, l = tid & 63;
    int lc = l & 31, lh = l >> 5;
    int hb4 = lh * 4;

    // i-fragments: B[k][n]: n=lane&31=i, k=(lane>>5)*8+e. Slice 4 = consts:
    // k=64,65 -> -0.5 (xx fold), k=66 -> 128.0 (bias), rest 0.
    short8 ifrag[5];
    {
        const u16* ip = xpk + ((size_t)b * NN + i0 + w * 32 + lc) * RSTRIDE + lh * 8;
#pragma unroll
        for (int ks = 0; ks < 4; ks++) ifrag[ks] = *(const short8*)(ip + ks * 16);
        short8 f4 = {0, 0, 0, 0, 0, 0, 0, 0};
        if (lh == 0) {
            f4[0] = (short)0xBF00;  // bf16(-0.5)
            f4[1] = (short)0xBF00;
            f4[2] = (short)0x4300;  // bf16(128.0)
        }
        ifrag[4] = f4;
    }

    u32 v0 = 0, v1 = 0, v2 = 0, v3 = 0;  // sorted desc keys (score|index)

#define CE(a, b) { u32 mx_ = umx(a, b); b = umn(a, b); a = mx_; }

#define STAGE(rr, bf)                                                              \
    {                                                                              \
        int jb = j00 + (rr) * 64;                                                  \
        for (int g = tid; g < 640; g += 256) {                                     \
            int rw = g / 10, c = g - rw * 10;                                      \
            uint4 u = *(const uint4*)(xpk + ((size_t)b * NN + jb + rw) * RSTRIDE + \
                                      c * 8);                                      \
            int sub = rw >> 5, r32 = rw & 31;                                      \
            *(uint4*)((char*)Bb + (bf) * 10240 + sub * 5120 + c * 512 +            \
                      ((r32 ^ (c & 7)) * 16)) = u;                                 \
        }                                                                          \
    }

    STAGE(0, 0);

    for (int r = 0; r < JPER / 64; r++) {
        __syncthreads();  // buf[r&1] ready; prev reads of buf[(r+1)&1] done
        if (r + 1 < JPER / 64) STAGE(r + 1, (r + 1) & 1);

        const char* bufp = (const char*)Bb + (r & 1) * 10240;
        f32x16 acc0, acc1;
#pragma unroll
        for (int e = 0; e < 16; e++) {
            acc0[e] = 0.f;
            acc1[e] = 0.f;
        }
#pragma unroll
        for (int ks = 0; ks < 5; ks++) {
            int c = ks * 2 + lh;
            int boff = c * 512 + ((lc ^ (c & 7)) * 16);
            short8 a0 = *(const short8*)(bufp + boff);
            short8 a1 = *(const short8*)(bufp + 5120 + boff);
            acc0 = __builtin_amdgcn_mfma_f32_32x32x16_bf16(a0, ifrag[ks], acc0, 0, 0, 0);
            acc1 = __builtin_amdgcn_mfma_f32_32x32x16_bf16(a1, ifrag[ks], acc1, 0, 0, 0);
        }
#pragma unroll
        for (int sub = 0; sub < 2; sub++) {
            const f32x16& acc = sub ? acc1 : acc0;
            int jlb = r * 64 + sub * 32 + hb4;  // j-local base (9 bits total)
            u32 kk[16];
#pragma unroll
            for (int rg = 0; rg < 16; rg++) {
                u32 u;
                float f = acc[rg];
                __builtin_memcpy(&u, &f, 4);
                int coff = (rg & 3) + 8 * (rg >> 2);
                kk[rg] = (u & ~0x1FFu) | (u32)(jlb + coff);
            }
            // sort each quad desc (5 CE each)
#pragma unroll
            for (int q = 0; q < 4; q++) {
                int p = q * 4;
                CE(kk[p + 0], kk[p + 2]); CE(kk[p + 1], kk[p + 3]);
                CE(kk[p + 0], kk[p + 1]); CE(kk[p + 2], kk[p + 3]);
                CE(kk[p + 1], kk[p + 2]);
            }
            // top4of8(quad0, quad1) -> kk[0..3]
            kk[0] = umx(kk[0], kk[7]); kk[1] = umx(kk[1], kk[6]);
            kk[2] = umx(kk[2], kk[5]); kk[3] = umx(kk[3], kk[4]);
            CE(kk[0], kk[2]); CE(kk[1], kk[3]); CE(kk[0], kk[1]); CE(kk[2], kk[3]);
            // top4of8(quad2, quad3) -> kk[8..11]
            kk[8] = umx(kk[8], kk[15]); kk[9] = umx(kk[9], kk[14]);
            kk[10] = umx(kk[10], kk[13]); kk[11] = umx(kk[11], kk[12]);
            CE(kk[8], kk[10]); CE(kk[9], kk[11]); CE(kk[8], kk[9]); CE(kk[10], kk[11]);
            // top4of8 -> kk[0..3]
            kk[0] = umx(kk[0], kk[11]); kk[1] = umx(kk[1], kk[10]);
            kk[2] = umx(kk[2], kk[9]); kk[3] = umx(kk[3], kk[8]);
            CE(kk[0], kk[2]); CE(kk[1], kk[3]); CE(kk[0], kk[1]); CE(kk[2], kk[3]);
            // merge with running v (sorted desc)
            v0 = umx(v0, kk[3]); v1 = umx(v1, kk[2]);
            v2 = umx(v2, kk[1]); v3 = umx(v3, kk[0]);
            CE(v0, v2); CE(v1, v3); CE(v0, v1); CE(v2, v3);
        }
    }
#undef STAGE
#undef CE

    size_t cb = ((size_t)b * NN + i0 + w * 32 + lc) * NCAND + part * 8 + lh * 4;
    cand[cb + 0] = (u16)(j00 + (v0 & 0x1FF));
    cand[cb + 1] = (u16)(j00 + (v1 & 0x1FF));
    cand[cb + 2] = (u16)(j00 + (v2 & 0x1FF));
    cand[cb + 3] = (u16)(j00 + (v3 & 0x1FF));
}

// K3: fp64 refine v7 — wave-per-point with LDS transpose: stage the 32
// candidate rows in wave-private LDS (coalesced), then each lane computes
// one candidate-half dot ENTIRELY in-lane (8 ds_read_b128 + fp64 FMA) and
// combines halves with ONE shfl. Kills the 4-step fp64 butterflies
// (256 ds-ops/thread -> ~30). Lane 0 does the serial top-4 (same tie-break).
__global__ __launch_bounds__(256) void k_knn_merge(const float* __restrict__ xt,
                                                   const double* __restrict__ xx64,
                                                   const u16* __restrict__ cand,
                                                   int* __restrict__ nidx) {
    __shared__ __align__(16) char rows[4 * 32 * 272];  // 34816 B (wave-private slices)
    __shared__ double svp[4 * 32];
    __shared__ double sxx[4 * 32];
    __shared__ u16 jc[4 * 32];

    int tid = threadIdx.x;
    int w = tid >> 6;   // wave = local point 0..3
    int l = tid & 63;
    // bijective XCD swizzle (gridDim.x = 8192, divisible by 8)
    int nwg8 = (int)(gridDim.x >> 3);
    int swz = (blockIdx.x & 7) * nwg8 + (blockIdx.x >> 3);
    size_t gp0 = (size_t)swz * 4;        // = b*NN + i0
    size_t bbase = (gp0 >> 11) << 11;    // b*NN
    size_t pt = gp0 + w;                 // this wave's point

    if (l < 32) {
        u16 j = cand[pt * NCAND + l];
        jc[w * 32 + l] = j;
        sxx[w * 32 + l] = xx64[bbase + j];
    }
    __syncthreads();

    char* myrows = rows + w * 32 * 272;

    // stage 32 candidate rows; chunk c of row r -> slot c ^ ((r&7)<<1)
    {
        int c = l & 15;
        int r0 = l >> 4;  // 0..3
#pragma unroll
        for (int it = 0; it < 8; it++) {
            int r = it * 4 + r0;
            int j = jc[w * 32 + r];
            float4 v = *(const float4*)(xt + (bbase + (size_t)j) * CC + c * 4);
            int slot = c ^ ((r & 7) << 1);
            *(float4*)(myrows + r * 272 + slot * 16) = v;
        }
    }
    // same-wave DS ordering: staging writes complete before this wave's reads

    // lane-local dot: candidate k = l>>1, half h = l&1 (floats [h*32, h*32+32))
    int k = l >> 1, h = l & 1;
    const float4* ap = (const float4*)(xt + pt * CC + h * 32);
    double d = 0.0;
    {
        const char* rb = myrows + k * 272;
#pragma unroll
        for (int i = 0; i < 8; i++) {
            int cj = h * 8 + i;
            int slot = cj ^ ((k & 7) << 1);
            float4 bv = *(const float4*)(rb + slot * 16);
            float4 av = ap[i];
            d += (double)av.x * bv.x + (double)av.y * bv.y +
                 (double)av.z * bv.z + (double)av.w * bv.w;
        }
    }
    d += __shfl_xor(d, 1);  // combine the two halves of candidate k
    if (h == 0) svp[w * 32 + k] = 2.0 * d - sxx[w * 32 + k];

    // selector: lane 0 per wave does the 32 -> top-4 insertion (tie: min idx)
    if (l == 0) {
        double v4[4];
        int id4[4];
#pragma unroll
        for (int s = 0; s < 4; s++) {
            v4[s] = -1e300;
            id4[s] = 0x7fffffff;
        }
        for (int cc = 0; cc < NCAND; cc++) {
            double cv = svp[w * 32 + cc];
            int ci = jc[w * 32 + cc];
#pragma unroll
            for (int s = 0; s < 4; s++) {
                bool take = (cv > v4[s]) || (cv == v4[s] && ci < id4[s]);
                double nv = take ? cv : v4[s];
                int ni = take ? ci : id4[s];
                double ov = take ? v4[s] : cv;
                int oi = take ? id4[s] : ci;
                v4[s] = nv;
                id4[s] = ni;
                cv = ov;
                ci = oi;
            }
        }
#pragma unroll
        for (int s = 0; s < 4; s++) nidx[pt * 4 + s] = id4[s];
    }
}

// K4: fused MFMA MLP. Wave w owns a CHANNEL slice: loads only its own
// weight frags (18 vs 80) and loops the 4 item groups.
__global__ __launch_bounds__(256) void k_mlp(const u16* __restrict__ xpk,
                                             const int* __restrict__ nidx,
                                             const u16* __restrict__ wb1,
                                             const u16* __restrict__ wb2,
                                             const u16* __restrict__ wb3,
                                             const float* __restrict__ b1,
                                             const float* __restrict__ b2,
                                             const float* __restrict__ b3,
                                             float* __restrict__ out) {
    int nch = blockIdx.x;  // 0..127
    int b = blockIdx.y;
    int n0 = nch * 16;
    int tid = threadIdx.x;

    __shared__ u16 Fb[64 * 128];   // raw features bf16, swizzled (16 KB)
    __shared__ u16 E1b[64 * 64];   // relu(e1) (8 KB)
    __shared__ u16 E2b[64 * 128];  // relu(e2) (16 KB)
    __shared__ float Ob[64 * 36];  // e3 k-maxed, padded (9 KB)
    __shared__ int ji[64];

    if (tid < 64) ji[tid] = nidx[((size_t)b * NN + n0) * KK + tid];
    __syncthreads();

    // gather: F[item][0..63]=center, [64..127]=neighbor (swizzled bf16 copy)
    for (int g = tid; g < 64 * 16; g += 256) {
        int it = g >> 4, q = g & 15;
        int half = q >> 3, cq = q & 7;
        int srcn = half ? ji[it] : (n0 + (it >> 2));
        uint4 u = *(const uint4*)(xpk + ((size_t)b * NN + srcn) * RSTRIDE + cq * 8);
        int byte = (it * 256 + half * 128 + cq * 16) ^ ((it & 7) << 4);
        *(uint4*)((char*)Fb + byte) = u;
    }
    __syncthreads();

    int w = tid >> 6, l = tid & 63;
    int lr = l & 15, lg = l >> 4;

    // ---- e1: wave w computes channels w*16..w*16+15 for ALL 64 items ----
    {
        f32x4 acc[4];
#pragma unroll
        for (int g = 0; g < 4; g++) acc[g] = (f32x4){0.f, 0.f, 0.f, 0.f};
#pragma unroll
        for (int ks = 0; ks < 4; ks++) {
            short8 bw = *(const short8*)(wb1 + ((size_t)(w * 4 + ks) * 64 + l) * 8);
#pragma unroll
            for (int g = 0; g < 4; g++) {
                int arow = g * 16 + lr;
                int off = (arow * 256 + ks * 64 + lg * 16) ^ ((arow & 7) << 4);
                short8 a = *(const short8*)((const char*)Fb + off);
                acc[g] = __builtin_amdgcn_mfma_f32_16x16x32_bf16(a, bw, acc[g], 0, 0, 0);
            }
        }
        float bias = b1[w * 16 + lr];
#pragma unroll
        for (int g = 0; g < 4; g++) {
#pragma unroll
            for (int q = 0; q < 4; q++) {
                int item = g * 16 + lg * 4 + q;
                float vv = fmaxf(acc[g][q] + bias, 0.f);
                int byte = (item * 128 + (w * 16 + lr) * 2) ^ ((item & 7) << 4);
                *(u16*)((char*)E1b + byte) = f2bf(vv);
            }
        }
    }
    __syncthreads();

    // ---- e2: wave w computes channels (w*2..w*2+1)*16 for all items ----
    {
        f32x4 acc[4][2];
#pragma unroll
        for (int g = 0; g < 4; g++)
#pragma unroll
            for (int c2 = 0; c2 < 2; c2++) acc[g][c2] = (f32x4){0.f, 0.f, 0.f, 0.f};
#pragma unroll
        for (int ks = 0; ks < 6; ks++) {
            short8 bw0 = *(const short8*)(wb2 + ((size_t)((w * 2) * 6 + ks) * 64 + l) * 8);
            short8 bw1 = *(const short8*)(wb2 + ((size_t)((w * 2 + 1) * 6 + ks) * 64 + l) * 8);
#pragma unroll
            for (int g = 0; g < 4; g++) {
                int arow = g * 16 + lr;
                int aswz = (arow & 7) << 4;
                short8 a;
                if (ks < 2) {
                    int off = (arow * 128 + ks * 64 + lg * 16) ^ aswz;
                    a = *(const short8*)((const char*)E1b + off);
                } else {
                    int off = (arow * 256 + (ks - 2) * 64 + lg * 16) ^ aswz;
                    uint4 u = *(const uint4*)((const char*)Fb + off);
                    unsigned int m;
                    m = ((u.x >> 15) & 0x10001u) * 0xFFFFu; u.x &= ~m;
                    m = ((u.y >> 15) & 0x10001u) * 0xFFFFu; u.y &= ~m;
                    m = ((u.z >> 15) & 0x10001u) * 0xFFFFu; u.z &= ~m;
                    m = ((u.w >> 15) & 0x10001u) * 0xFFFFu; u.w &= ~m;
                    __builtin_memcpy(&a, &u, 16);
                }
                acc[g][0] = __builtin_amdgcn_mfma_f32_16x16x32_bf16(a, bw0, acc[g][0], 0, 0, 0);
                acc[g][1] = __builtin_amdgcn_mfma_f32_16x16x32_bf16(a, bw1, acc[g][1], 0, 0, 0);
            }
        }
#pragma unroll
        for (int c2 = 0; c2 < 2; c2++) {
            float bias = b2[(w * 2 + c2) * 16 + lr];
#pragma unroll
            for (int g = 0; g < 4; g++) {
#pragma unroll
                for (int q = 0; q < 4; q++) {
                    int item = g * 16 + lg * 4 + q;
                    float vv = fmaxf(acc[g][c2][q] + bias, 0.f);
                    int byte = (item * 256 + ((w * 2 + c2) * 16 + lr) * 2) ^ ((item & 7) << 4);
                    *(u16*)((char*)E2b + byte) = f2bf(vv);
                }
            }
        }
    }
    __syncthreads();

    // ---- e3: wave w computes channels w*16..+15; k-max in-lane ----
    {
        f32x4 acc[4][2];
#pragma unroll
        for (int g = 0; g < 4; g++)
#pragma unroll
            for (int r = 0; r < 2; r++) acc[g][r] = (f32x4){0.f, 0.f, 0.f, 0.f};
#pragma unroll
        for (int ks = 0; ks < 2; ks++) {
            short8 bw = *(const short8*)(wb3 + ((size_t)(w * 2 + ks) * 64 + l) * 8);
#pragma unroll
            for (int g = 0; g < 4; g++) {
                int arow = g * 16 + lr;
                int aswz = (arow & 7) << 4;
#pragma unroll
                for (int r = 0; r < 2; r++) {
                    int off = (arow * 256 + r * 128 + ks * 64 + lg * 16) ^ aswz;
                    short8 a = *(const short8*)((const char*)E2b + off);
                    acc[g][r] = __builtin_amdgcn_mfma_f32_16x16x32_bf16(a, bw, acc[g][r], 0, 0, 0);
                }
            }
        }
        float bias = b3[w * 16 + lr];
        int o = w * 16 + lr;
#pragma unroll
        for (int g = 0; g < 4; g++) {
            int nl = g * 4 + lg;
#pragma unroll
            for (int r = 0; r < 2; r++) {
                float m = fmaxf(fmaxf(acc[g][r][0], acc[g][r][1]),
                                fmaxf(acc[g][r][2], acc[g][r][3])) + bias;
                Ob[o * 36 + nl * 2 + r] = m;
            }
        }
    }
    __syncthreads();

    // coalesced store: thread t -> out channel t>>2, 8 floats
    {
        int o = tid >> 2, q = tid & 3;
        float4 v0 = *(const float4*)&Ob[o * 36 + q * 8];
        float4 v1 = *(const float4*)&Ob[o * 36 + q * 8 + 4];
        float* dst = out + ((size_t)(b * 64 + o)) * 4096 + n0 * 2 + q * 8;
        ((float4*)dst)[0] = v0;
        ((float4*)dst)[1] = v1;
    }
}

extern "C" void kernel_launch(void* const* d_in, const int* in_sizes, int n_in,
                              void* d_out, int out_size, void* d_ws, size_t ws_size,
                              hipStream_t stream) {
    const float* x = (const float*)d_in[0];
    const float* w1 = (const float*)d_in[1];
    const float* b1 = (const float*)d_in[2];
    const float* w2 = (const float*)d_in[3];
    const float* b2 = (const float*)d_in[4];
    const float* w3 = (const float*)d_in[5];
    const float* b3 = (const float*)d_in[6];
    float* out = (float*)d_out;

    // workspace layout (~16.1 MB)
    float* xt = (float*)d_ws;                          // B*N*C fp32 = 8 MB
    u16* xpk = (u16*)(xt + (size_t)BB * NN * CC);      // B*N*80 bf16 = 5.24 MB
    double* xx64 = (double*)(xpk + (size_t)BB * NN * RSTRIDE);  // B*N fp64 = 262 KB
    int* nidx = (int*)(xx64 + (size_t)BB * NN);        // B*N*K = 0.5 MB
    u16* cand = (u16*)(nidx + (size_t)BB * NN * KK);   // B*N*32 u16 = 2 MB
    u16* wb1 = cand + (size_t)BB * NN * NCAND;
    u16* wb2 = wb1 + 64 * 128;
    u16* wb3 = wb2 + 128 * 192;

    k_prep<<<dim3(NN / 256, BB), 256, 0, stream>>>(x, xt, xx64, xpk);
    k_wprep<<<dim3(32), 256, 0, stream>>>(w1, w2, w3, wb1, wb2, wb3);
    k_knn3<<<dim3(NN / 128, NPART, BB), 256, 0, stream>>>(xpk, cand);
    k_knn_merge<<<dim3(BB * NN / 4), 256, 0, stream>>>(xt, xx64, cand, nidx);
    k_mlp<<<dim3(NN / 16, BB), 256, 0, stream>>>(xpk, nidx, wb1, wb2, wb3, b1, b2, b3, out);
}

// Round 27
// 115.730 us; speedup vs baseline: 1.4340x; 1.4340x over previous
//
#include <hip/hip_runtime.h>
#include <hip/hip_bf16.h>

#define BB 16
#define CC 64
#define NN 2048
#define KK 4
#define NPART 4
#define JPER (NN / NPART)
#define NCAND 32
#define RSTRIDE 80  // bf16/row: 64 coords + xx_hi + xx_lo + one(=1.0) + 13 zeros

typedef unsigned short u16;
typedef unsigned int u32;
typedef __attribute__((ext_vector_type(4))) float f32x4;
typedef __attribute__((ext_vector_type(16))) float f32x16;
typedef __attribute__((ext_vector_type(8))) short short8;

__device__ __forceinline__ float bf2f(u16 u) {
    unsigned int x = ((unsigned int)u) << 16;
    float f;
    __builtin_memcpy(&f, &x, 4);
    return f;
}
__device__ __forceinline__ u16 f2bf(float f) {
    __hip_bfloat16 h = __float2bfloat16(f);
    u16 u;
    __builtin_memcpy(&u, &h, 2);
    return u;
}
__device__ __forceinline__ unsigned int pk2(float a, float b) {
    return (unsigned int)f2bf(a) | ((unsigned int)f2bf(b) << 16);
}
__device__ __forceinline__ u32 umx(u32 a, u32 b) { return a > b ? a : b; }
__device__ __forceinline__ u32 umn(u32 a, u32 b) { return a < b ? a : b; }

// K1: transpose x -> xt fp32, xx64 fp64, and xpk (B,N,80) bf16:
// [0..63]=x, [64]=xx_hi, [65]=xx_lo, [66]=1.0, [67..79]=0.
__global__ __launch_bounds__(256) void k_prep(const float* __restrict__ x,
                                              float* __restrict__ xt,
                                              double* __restrict__ xx64,
                                              u16* __restrict__ xpk) {
    int b = blockIdx.y;
    int n = blockIdx.x * 256 + threadIdx.x;
    const float* xb = x + (size_t)b * CC * NN;
    float v[CC];
    float s = 0.f;
    double s64 = 0.0;
#pragma unroll
    for (int c = 0; c < CC; c++) {
        v[c] = xb[(size_t)c * NN + n];
        s = fmaf(v[c], v[c], s);
        s64 += (double)v[c] * (double)v[c];
    }
    float4* dst = (float4*)(xt + ((size_t)b * NN + n) * CC);
#pragma unroll
    for (int q = 0; q < 16; q++) {
        dst[q] = make_float4(v[4 * q], v[4 * q + 1], v[4 * q + 2], v[4 * q + 3]);
    }
    xx64[b * NN + n] = s64;
    u16* dp = xpk + ((size_t)b * NN + n) * RSTRIDE;
#pragma unroll
    for (int q = 0; q < 8; q++) {
        uint4 u;
        u.x = pk2(v[8 * q], v[8 * q + 1]);
        u.y = pk2(v[8 * q + 2], v[8 * q + 3]);
        u.z = pk2(v[8 * q + 4], v[8 * q + 5]);
        u.w = pk2(v[8 * q + 6], v[8 * q + 7]);
        *(uint4*)(dp + q * 8) = u;
    }
    u16 hi = f2bf(s);
    u16 lo = f2bf(s - bf2f(hi));
    uint4 u8;
    u8.x = (unsigned int)hi | ((unsigned int)lo << 16);
    u8.y = 0x00003F80u;  // [66] = bf16(1.0)  (bias column)
    u8.z = 0; u8.w = 0;
    *(uint4*)(dp + 64) = u8;
    uint4 z = {0, 0, 0, 0};
    *(uint4*)(dp + 72) = z;
}

// K1b: pack weights to bf16 fragment-linear layout (for 16x16x32 MLP mfma).
__global__ __launch_bounds__(256) void k_wprep(const float* __restrict__ w1,
                                               const float* __restrict__ w2,
                                               const float* __restrict__ w3,
                                               u16* __restrict__ wb1,
                                               u16* __restrict__ wb2,
                                               u16* __restrict__ wb3) {
    int t = blockIdx.x * 256 + threadIdx.x;
    int stride = gridDim.x * 256;
    for (int idx = t; idx < 64 * 128; idx += stride) {  // w1: 64 out x 128 k
        int o = idx >> 7, k = idx & 127;
        int cb = o >> 4, lr = o & 15, ks = k >> 5, g = (k >> 3) & 3, e = k & 7;
        wb1[((cb * 4 + ks) * 64 + g * 16 + lr) * 8 + e] = f2bf(w1[idx]);
    }
    for (int idx = t; idx < 128 * 192; idx += stride) {  // w2: 128 out x 192 k
        int o = idx / 192, k = idx - o * 192;
        int cb = o >> 4, lr = o & 15, ks = k >> 5, g = (k >> 3) & 3, e = k & 7;
        wb2[((cb * 6 + ks) * 64 + g * 16 + lr) * 8 + e] = f2bf(w2[idx]);
    }
    for (int idx = t; idx < 64 * 64; idx += stride) {  // w3: 64 out x 64 k
        int o = idx >> 6, k = idx & 63;
        int cb = o >> 4, lr = o & 15, ks = k >> 5, g = (k >> 3) & 3, e = k & 7;
        wb3[((cb * 2 + ks) * 64 + g * 16 + lr) * 8 + e] = f2bf(w3[idx]);
    }
}

// K2: swapped-operand MFMA KNN, K=80. acc = dot - xx_j/2 + 128 (>0), so fp32
// bits order as u32. 9-bit j-local index packed into low mantissa bits;
// branchless sorting networks. Top-4 per lane half-stream -> 32 cand/i.
__global__ __launch_bounds__(256) void k_knn3(const u16* __restrict__ xpk,
                                              u16* __restrict__ cand) {
    int ib = blockIdx.x;   // 0..15  (128 i-rows each)
    int part = blockIdx.y; // 0..NPART-1
    int b = blockIdx.z;
    int tid = threadIdx.x;
    int i0 = ib * 128;
    int j00 = part * JPER;

    // Bb: [buf][sub][chunk 0..9][slot=r32^(c&7)][16B]
    __shared__ u16 Bb[2 * 2 * 10 * 32 * 8];  // 20 KB

    int w = tid >> 6, l = tid & 63;
    int lc = l & 31, lh = l >> 5;
    int hb4 = lh * 4;

    // i-fragments: B[k][n]: n=lane&31=i, k=(lane>>5)*8+e. Slice 4 = consts:
    // k=64,65 -> -0.5 (xx fold), k=66 -> 128.0 (bias), rest 0.
    short8 ifrag[5];
    {
        const u16* ip = xpk + ((size_t)b * NN + i0 + w * 32 + lc) * RSTRIDE + lh * 8;
#pragma unroll
        for (int ks = 0; ks < 4; ks++) ifrag[ks] = *(const short8*)(ip + ks * 16);
        short8 f4 = {0, 0, 0, 0, 0, 0, 0, 0};
        if (lh == 0) {
            f4[0] = (short)0xBF00;  // bf16(-0.5)
            f4[1] = (short)0xBF00;
            f4[2] = (short)0x4300;  // bf16(128.0)
        }
        ifrag[4] = f4;
    }

    u32 v0 = 0, v1 = 0, v2 = 0, v3 = 0;  // sorted desc keys (score|index)

#define CE(a, b) { u32 mx_ = umx(a, b); b = umn(a, b); a = mx_; }

#define STAGE(rr, bf)                                                              \
    {                                                                              \
        int jb = j00 + (rr) * 64;                                                  \
        for (int g = tid; g < 640; g += 256) {                                     \
            int rw = g / 10, c = g - rw * 10;                                      \
            uint4 u = *(const uint4*)(xpk + ((size_t)b * NN + jb + rw) * RSTRIDE + \
                                      c * 8);                                      \
            int sub = rw >> 5, r32 = rw & 31;                                      \
            *(uint4*)((char*)Bb + (bf) * 10240 + sub * 5120 + c * 512 +            \
                      ((r32 ^ (c & 7)) * 16)) = u;                                 \
        }                                                                          \
    }

    STAGE(0, 0);

    for (int r = 0; r < JPER / 64; r++) {
        __syncthreads();  // buf[r&1] ready; prev reads of buf[(r+1)&1] done
        if (r + 1 < JPER / 64) STAGE(r + 1, (r + 1) & 1);

        const char* bufp = (const char*)Bb + (r & 1) * 10240;
        f32x16 acc0, acc1;
#pragma unroll
        for (int e = 0; e < 16; e++) {
            acc0[e] = 0.f;
            acc1[e] = 0.f;
        }
#pragma unroll
        for (int ks = 0; ks < 5; ks++) {
            int c = ks * 2 + lh;
            int boff = c * 512 + ((lc ^ (c & 7)) * 16);
            short8 a0 = *(const short8*)(bufp + boff);
            short8 a1 = *(const short8*)(bufp + 5120 + boff);
            acc0 = __builtin_amdgcn_mfma_f32_32x32x16_bf16(a0, ifrag[ks], acc0, 0, 0, 0);
            acc1 = __builtin_amdgcn_mfma_f32_32x32x16_bf16(a1, ifrag[ks], acc1, 0, 0, 0);
        }
#pragma unroll
        for (int sub = 0; sub < 2; sub++) {
            const f32x16& acc = sub ? acc1 : acc0;
            int jlb = r * 64 + sub * 32 + hb4;  // j-local base (9 bits total)
            u32 kk[16];
#pragma unroll
            for (int rg = 0; rg < 16; rg++) {
                u32 u;
                float f = acc[rg];
                __builtin_memcpy(&u, &f, 4);
                int coff = (rg & 3) + 8 * (rg >> 2);
                kk[rg] = (u & ~0x1FFu) | (u32)(jlb + coff);
            }
            // sort each quad desc (5 CE each)
#pragma unroll
            for (int q = 0; q < 4; q++) {
                int p = q * 4;
                CE(kk[p + 0], kk[p + 2]); CE(kk[p + 1], kk[p + 3]);
                CE(kk[p + 0], kk[p + 1]); CE(kk[p + 2], kk[p + 3]);
                CE(kk[p + 1], kk[p + 2]);
            }
            // top4of8(quad0, quad1) -> kk[0..3]
            kk[0] = umx(kk[0], kk[7]); kk[1] = umx(kk[1], kk[6]);
            kk[2] = umx(kk[2], kk[5]); kk[3] = umx(kk[3], kk[4]);
            CE(kk[0], kk[2]); CE(kk[1], kk[3]); CE(kk[0], kk[1]); CE(kk[2], kk[3]);
            // top4of8(quad2, quad3) -> kk[8..11]
            kk[8] = umx(kk[8], kk[15]); kk[9] = umx(kk[9], kk[14]);
            kk[10] = umx(kk[10], kk[13]); kk[11] = umx(kk[11], kk[12]);
            CE(kk[8], kk[10]); CE(kk[9], kk[11]); CE(kk[8], kk[9]); CE(kk[10], kk[11]);
            // top4of8 -> kk[0..3]
            kk[0] = umx(kk[0], kk[11]); kk[1] = umx(kk[1], kk[10]);
            kk[2] = umx(kk[2], kk[9]); kk[3] = umx(kk[3], kk[8]);
            CE(kk[0], kk[2]); CE(kk[1], kk[3]); CE(kk[0], kk[1]); CE(kk[2], kk[3]);
            // merge with running v (sorted desc)
            v0 = umx(v0, kk[3]); v1 = umx(v1, kk[2]);
            v2 = umx(v2, kk[1]); v3 = umx(v3, kk[0]);
            CE(v0, v2); CE(v1, v3); CE(v0, v1); CE(v2, v3);
        }
    }
#undef STAGE
#undef CE

    size_t cb = ((size_t)b * NN + i0 + w * 32 + lc) * NCAND + part * 8 + lh * 4;
    cand[cb + 0] = (u16)(j00 + (v0 & 0x1FF));
    cand[cb + 1] = (u16)(j00 + (v1 & 0x1FF));
    cand[cb + 2] = (u16)(j00 + (v2 & 0x1FF));
    cand[cb + 3] = (u16)(j00 + (v3 & 0x1FF));
}

// K3: fp64 refine, 16-lane coop, TWO point-groups per block (1024 blocks):
// phase A stages jc/sxx for both groups; phase B runs both groups' gather+
// dot sweeps back-to-back with NO intervening barrier (disjoint sv regions)
// so group-1 loads overlap group-0 drain; phase C selects 32 points in
// parallel. XCD swizzle keeps gathers L2-local.
__global__ __launch_bounds__(256) void k_knn_merge(const float* __restrict__ xt,
                                                   const double* __restrict__ xx64,
                                                   const u16* __restrict__ cand,
                                                   int* __restrict__ nidx) {
    __shared__ double sv[2][16 * 33];
    __shared__ double sxx[2][16 * 33];
    __shared__ u16 jc[2][16 * 33];

    int tid = threadIdx.x;
    // bijective XCD swizzle (gridDim.x = 1024, divisible by 8)
    int nwg8 = (int)(gridDim.x >> 3);
    int swz = (blockIdx.x & 7) * nwg8 + (blockIdx.x >> 3);
    size_t base_pt = (size_t)swz * 32;       // 32 consecutive points (one batch)
    size_t bbase = (base_pt >> 11) << 11;    // b*NN

    // phase A: stage candidate ids + ||xj||^2 for both groups
    for (int idx = tid; idx < 2 * 16 * 32; idx += 256) {
        int it = idx >> 9, p = (idx >> 5) & 15, c = idx & 31;
        u16 j = cand[(base_pt + it * 16 + p) * NCAND + c];
        jc[it][p * 33 + c] = j;
        sxx[it][p * 33 + c] = xx64[bbase + j];
    }
    __syncthreads();

    int g = tid >> 4;   // local point 0..15
    int q = tid & 15;   // chunk lane

    // phase B: both groups, no barrier between (independent sv regions)
    for (int it = 0; it < 2; it++) {
        size_t pt = base_pt + it * 16 + g;
        float4 a = ((const float4*)(xt + pt * CC))[q];
        for (int c0 = 0; c0 < NCAND; c0 += 4) {
            int j0 = jc[it][g * 33 + c0 + 0];
            int j1 = jc[it][g * 33 + c0 + 1];
            int j2 = jc[it][g * 33 + c0 + 2];
            int j3 = jc[it][g * 33 + c0 + 3];
            float4 b0 = ((const float4*)(xt + (bbase + j0) * CC))[q];
            float4 b1 = ((const float4*)(xt + (bbase + j1) * CC))[q];
            float4 b2 = ((const float4*)(xt + (bbase + j2) * CC))[q];
            float4 b3 = ((const float4*)(xt + (bbase + j3) * CC))[q];
            double d0 = (double)a.x * b0.x + (double)a.y * b0.y +
                        (double)a.z * b0.z + (double)a.w * b0.w;
            double d1 = (double)a.x * b1.x + (double)a.y * b1.y +
                        (double)a.z * b1.z + (double)a.w * b1.w;
            double d2 = (double)a.x * b2.x + (double)a.y * b2.y +
                        (double)a.z * b2.z + (double)a.w * b2.w;
            double d3 = (double)a.x * b3.x + (double)a.y * b3.y +
                        (double)a.z * b3.z + (double)a.w * b3.w;
            d0 += __shfl_xor(d0, 8); d1 += __shfl_xor(d1, 8);
            d2 += __shfl_xor(d2, 8); d3 += __shfl_xor(d3, 8);
            d0 += __shfl_xor(d0, 4); d1 += __shfl_xor(d1, 4);
            d2 += __shfl_xor(d2, 4); d3 += __shfl_xor(d3, 4);
            d0 += __shfl_xor(d0, 2); d1 += __shfl_xor(d1, 2);
            d2 += __shfl_xor(d2, 2); d3 += __shfl_xor(d3, 2);
            d0 += __shfl_xor(d0, 1); d1 += __shfl_xor(d1, 1);
            d2 += __shfl_xor(d2, 1); d3 += __shfl_xor(d3, 1);
            if (q == 0) {
                sv[it][g * 33 + c0 + 0] = 2.0 * d0 - sxx[it][g * 33 + c0 + 0];
                sv[it][g * 33 + c0 + 1] = 2.0 * d1 - sxx[it][g * 33 + c0 + 1];
                sv[it][g * 33 + c0 + 2] = 2.0 * d2 - sxx[it][g * 33 + c0 + 2];
                sv[it][g * 33 + c0 + 3] = 2.0 * d3 - sxx[it][g * 33 + c0 + 3];
            }
        }
    }
    __syncthreads();

    // phase C: 32 selectors in parallel (tie: min idx)
    if (tid < 32) {
        int it = tid >> 4, p = tid & 15;
        double v4[4];
        int id4[4];
#pragma unroll
        for (int s = 0; s < 4; s++) {
            v4[s] = -1e300;
            id4[s] = 0x7fffffff;
        }
        for (int cc = 0; cc < NCAND; cc++) {
            double cv = sv[it][p * 33 + cc];
            int ci = jc[it][p * 33 + cc];
#pragma unroll
            for (int s = 0; s < 4; s++) {
                bool take = (cv > v4[s]) || (cv == v4[s] && ci < id4[s]);
                double nv = take ? cv : v4[s];
                int ni = take ? ci : id4[s];
                double ov = take ? v4[s] : cv;
                int oi = take ? id4[s] : ci;
                v4[s] = nv;
                id4[s] = ni;
                cv = ov;
                ci = oi;
            }
        }
        size_t pt = base_pt + it * 16 + p;
#pragma unroll
        for (int s = 0; s < 4; s++) nidx[pt * 4 + s] = id4[s];
    }
}

// K4: fused MFMA MLP. Wave w owns a CHANNEL slice: loads only its own
// weight frags (18 vs 80) and loops the 4 item groups.
__global__ __launch_bounds__(256) void k_mlp(const u16* __restrict__ xpk,
                                             const int* __restrict__ nidx,
                                             const u16* __restrict__ wb1,
                                             const u16* __restrict__ wb2,
                                             const u16* __restrict__ wb3,
                                             const float* __restrict__ b1,
                                             const float* __restrict__ b2,
                                             const float* __restrict__ b3,
                                             float* __restrict__ out) {
    int nch = blockIdx.x;  // 0..127
    int b = blockIdx.y;
    int n0 = nch * 16;
    int tid = threadIdx.x;

    __shared__ u16 Fb[64 * 128];   // raw features bf16, swizzled (16 KB)
    __shared__ u16 E1b[64 * 64];   // relu(e1) (8 KB)
    __shared__ u16 E2b[64 * 128];  // relu(e2) (16 KB)
    __shared__ float Ob[64 * 36];  // e3 k-maxed, padded (9 KB)
    __shared__ int ji[64];

    if (tid < 64) ji[tid] = nidx[((size_t)b * NN + n0) * KK + tid];
    __syncthreads();

    // gather: F[item][0..63]=center, [64..127]=neighbor (swizzled bf16 copy)
    for (int g = tid; g < 64 * 16; g += 256) {
        int it = g >> 4, q = g & 15;
        int half = q >> 3, cq = q & 7;
        int srcn = half ? ji[it] : (n0 + (it >> 2));
        uint4 u = *(const uint4*)(xpk + ((size_t)b * NN + srcn) * RSTRIDE + cq * 8);
        int byte = (it * 256 + half * 128 + cq * 16) ^ ((it & 7) << 4);
        *(uint4*)((char*)Fb + byte) = u;
    }
    __syncthreads();

    int w = tid >> 6, l = tid & 63;
    int lr = l & 15, lg = l >> 4;

    // ---- e1: wave w computes channels w*16..w*16+15 for ALL 64 items ----
    {
        f32x4 acc[4];
#pragma unroll
        for (int g = 0; g < 4; g++) acc[g] = (f32x4){0.f, 0.f, 0.f, 0.f};
#pragma unroll
        for (int ks = 0; ks < 4; ks++) {
            short8 bw = *(const short8*)(wb1 + ((size_t)(w * 4 + ks) * 64 + l) * 8);
#pragma unroll
            for (int g = 0; g < 4; g++) {
                int arow = g * 16 + lr;
                int off = (arow * 256 + ks * 64 + lg * 16) ^ ((arow & 7) << 4);
                short8 a = *(const short8*)((const char*)Fb + off);
                acc[g] = __builtin_amdgcn_mfma_f32_16x16x32_bf16(a, bw, acc[g], 0, 0, 0);
            }
        }
        float bias = b1[w * 16 + lr];
#pragma unroll
        for (int g = 0; g < 4; g++) {
#pragma unroll
            for (int q = 0; q < 4; q++) {
                int item = g * 16 + lg * 4 + q;
                float vv = fmaxf(acc[g][q] + bias, 0.f);
                int byte = (item * 128 + (w * 16 + lr) * 2) ^ ((item & 7) << 4);
                *(u16*)((char*)E1b + byte) = f2bf(vv);
            }
        }
    }
    __syncthreads();

    // ---- e2: wave w computes channels (w*2..w*2+1)*16 for all items ----
    {
        f32x4 acc[4][2];
#pragma unroll
        for (int g = 0; g < 4; g++)
#pragma unroll
            for (int c2 = 0; c2 < 2; c2++) acc[g][c2] = (f32x4){0.f, 0.f, 0.f, 0.f};
#pragma unroll
        for (int ks = 0; ks < 6; ks++) {
            short8 bw0 = *(const short8*)(wb2 + ((size_t)((w * 2) * 6 + ks) * 64 + l) * 8);
            short8 bw1 = *(const short8*)(wb2 + ((size_t)((w * 2 + 1) * 6 + ks) * 64 + l) * 8);
#pragma unroll
            for (int g = 0; g < 4; g++) {
                int arow = g * 16 + lr;
                int aswz = (arow & 7) << 4;
                short8 a;
                if (ks < 2) {
                    int off = (arow * 128 + ks * 64 + lg * 16) ^ aswz;
                    a = *(const short8*)((const char*)E1b + off);
                } else {
                    int off = (arow * 256 + (ks - 2) * 64 + lg * 16) ^ aswz;
                    uint4 u = *(const uint4*)((const char*)Fb + off);
                    unsigned int m;
                    m = ((u.x >> 15) & 0x10001u) * 0xFFFFu; u.x &= ~m;
                    m = ((u.y >> 15) & 0x10001u) * 0xFFFFu; u.y &= ~m;
                    m = ((u.z >> 15) & 0x10001u) * 0xFFFFu; u.z &= ~m;
                    m = ((u.w >> 15) & 0x10001u) * 0xFFFFu; u.w &= ~m;
                    __builtin_memcpy(&a, &u, 16);
                }
                acc[g][0] = __builtin_amdgcn_mfma_f32_16x16x32_bf16(a, bw0, acc[g][0], 0, 0, 0);
                acc[g][1] = __builtin_amdgcn_mfma_f32_16x16x32_bf16(a, bw1, acc[g][1], 0, 0, 0);
            }
        }
#pragma unroll
        for (int c2 = 0; c2 < 2; c2++) {
            float bias = b2[(w * 2 + c2) * 16 + lr];
#pragma unroll
            for (int g = 0; g < 4; g++) {
#pragma unroll
                for (int q = 0; q < 4; q++) {
                    int item = g * 16 + lg * 4 + q;
                    float vv = fmaxf(acc[g][c2][q] + bias, 0.f);
                    int byte = (item * 256 + ((w * 2 + c2) * 16 + lr) * 2) ^ ((item & 7) << 4);
                    *(u16*)((char*)E2b + byte) = f2bf(vv);
                }
            }
        }
    }
    __syncthreads();

    // ---- e3: wave w computes channels w*16..+15; k-max in-lane ----
    {
        f32x4 acc[4][2];
#pragma unroll
        for (int g = 0; g < 4; g++)
#pragma unroll
            for (int r = 0; r < 2; r++) acc[g][r] = (f32x4){0.f, 0.f, 0.f, 0.f};
#pragma unroll
        for (int ks = 0; ks < 2; ks++) {
            short8 bw = *(const short8*)(wb3 + ((size_t)(w * 2 + ks) * 64 + l) * 8);
#pragma unroll
            for (int g = 0; g < 4; g++) {
                int arow = g * 16 + lr;
                int aswz = (arow & 7) << 4;
#pragma unroll
                for (int r = 0; r < 2; r++) {
                    int off = (arow * 256 + r * 128 + ks * 64 + lg * 16) ^ aswz;
                    short8 a = *(const short8*)((const char*)E2b + off);
                    acc[g][r] = __builtin_amdgcn_mfma_f32_16x16x32_bf16(a, bw, acc[g][r], 0, 0, 0);
                }
            }
        }
        float bias = b3[w * 16 + lr];
        int o = w * 16 + lr;
#pragma unroll
        for (int g = 0; g < 4; g++) {
            int nl = g * 4 + lg;
#pragma unroll
            for (int r = 0; r < 2; r++) {
                float m = fmaxf(fmaxf(acc[g][r][0], acc[g][r][1]),
                                fmaxf(acc[g][r][2], acc[g][r][3])) + bias;
                Ob[o * 36 + nl * 2 + r] = m;
            }
        }
    }
    __syncthreads();

    // coalesced store: thread t -> out channel t>>2, 8 floats
    {
        int o = tid >> 2, q = tid & 3;
        float4 v0 = *(const float4*)&Ob[o * 36 + q * 8];
        float4 v1 = *(const float4*)&Ob[o * 36 + q * 8 + 4];
        float* dst = out + ((size_t)(b * 64 + o)) * 4096 + n0 * 2 + q * 8;
        ((float4*)dst)[0] = v0;
        ((float4*)dst)[1] = v1;
    }
}

extern "C" void kernel_launch(void* const* d_in, const int* in_sizes, int n_in,
                              void* d_out, int out_size, void* d_ws, size_t ws_size,
                              hipStream_t stream) {
    const float* x = (const float*)d_in[0];
    const float* w1 = (const float*)d_in[1];
    const float* b1 = (const float*)d_in[2];
    const float* w2 = (const float*)d_in[3];
    const float* b2 = (const float*)d_in[4];
    const float* w3 = (const float*)d_in[5];
    const float* b3 = (const float*)d_in[6];
    float* out = (float*)d_out;

    // workspace layout (~16.1 MB)
    float* xt = (float*)d_ws;                          // B*N*C fp32 = 8 MB
    u16* xpk = (u16*)(xt + (size_t)BB * NN * CC);      // B*N*80 bf16 = 5.24 MB
    double* xx64 = (double*)(xpk + (size_t)BB * NN * RSTRIDE);  // B*N fp64 = 262 KB
    int* nidx = (int*)(xx64 + (size_t)BB * NN);        // B*N*K = 0.5 MB
    u16* cand = (u16*)(nidx + (size_t)BB * NN * KK);   // B*N*32 u16 = 2 MB
    u16* wb1 = cand + (size_t)BB * NN * NCAND;
    u16* wb2 = wb1 + 64 * 128;
    u16* wb3 = wb2 + 128 * 192;

    k_prep<<<dim3(NN / 256, BB), 256, 0, stream>>>(x, xt, xx64, xpk);
    k_wprep<<<dim3(32), 256, 0, stream>>>(w1, w2, w3, wb1, wb2, wb3);
    k_knn3<<<dim3(NN / 128, NPART, BB), 256, 0, stream>>>(xpk, cand);
    k_knn_merge<<<dim3(BB * NN / 32), 256, 0, stream>>>(xt, xx64, cand, nidx);
    k_mlp<<<dim3(NN / 16, BB), 256, 0, stream>>>(xpk, nidx, wb1, wb2, wb3, b1, b2, b3, out);
}

// Round 28
// 107.357 us; speedup vs baseline: 1.5458x; 1.0780x over previous
//
#include <hip/hip_runtime.h>
#include <hip/hip_bf16.h>

#define BB 16
#define CC 64
#define NN 2048
#define KK 4
#define NPART 4
#define JPER (NN / NPART)
#define NCAND 32
#define RSTRIDE 80  // bf16/row: 64 coords + xx_hi + xx_lo + one(=1.0) + 13 zeros

typedef unsigned short u16;
typedef unsigned int u32;
typedef __attribute__((ext_vector_type(4))) float f32x4;
typedef __attribute__((ext_vector_type(16))) float f32x16;
typedef __attribute__((ext_vector_type(8))) short short8;

__device__ __forceinline__ float bf2f(u16 u) {
    unsigned int x = ((unsigned int)u) << 16;
    float f;
    __builtin_memcpy(&f, &x, 4);
    return f;
}
__device__ __forceinline__ u16 f2bf(float f) {
    __hip_bfloat16 h = __float2bfloat16(f);
    u16 u;
    __builtin_memcpy(&u, &h, 2);
    return u;
}
__device__ __forceinline__ unsigned int pk2(float a, float b) {
    return (unsigned int)f2bf(a) | ((unsigned int)f2bf(b) << 16);
}
__device__ __forceinline__ u32 umx(u32 a, u32 b) { return a > b ? a : b; }
__device__ __forceinline__ u32 umn(u32 a, u32 b) { return a < b ? a : b; }

// K1: transpose x -> xt fp32, xx64 fp64, xpk (B,N,80) bf16, AND pack the
// MLP weights to fragment-linear bf16 (wprep fused: ~1 elem/thread).
__global__ __launch_bounds__(256) void k_prep(const float* __restrict__ x,
                                              float* __restrict__ xt,
                                              double* __restrict__ xx64,
                                              u16* __restrict__ xpk,
                                              const float* __restrict__ w1,
                                              const float* __restrict__ w2,
                                              const float* __restrict__ w3,
                                              u16* __restrict__ wb1,
                                              u16* __restrict__ wb2,
                                              u16* __restrict__ wb3) {
    int b = blockIdx.y;
    int n = blockIdx.x * 256 + threadIdx.x;

    // ---- fused weight packing (grid-stride over all 128 blocks) ----
    {
        int t = (blockIdx.y * gridDim.x + blockIdx.x) * 256 + threadIdx.x;
        int stride = gridDim.x * gridDim.y * 256;
        for (int idx = t; idx < 64 * 128; idx += stride) {  // w1
            int o = idx >> 7, k = idx & 127;
            int cb = o >> 4, lr = o & 15, ks = k >> 5, g = (k >> 3) & 3, e = k & 7;
            wb1[((cb * 4 + ks) * 64 + g * 16 + lr) * 8 + e] = f2bf(w1[idx]);
        }
        for (int idx = t; idx < 128 * 192; idx += stride) {  // w2
            int o = idx / 192, k = idx - o * 192;
            int cb = o >> 4, lr = o & 15, ks = k >> 5, g = (k >> 3) & 3, e = k & 7;
            wb2[((cb * 6 + ks) * 64 + g * 16 + lr) * 8 + e] = f2bf(w2[idx]);
        }
        for (int idx = t; idx < 64 * 64; idx += stride) {  // w3
            int o = idx >> 6, k = idx & 63;
            int cb = o >> 4, lr = o & 15, ks = k >> 5, g = (k >> 3) & 3, e = k & 7;
            wb3[((cb * 2 + ks) * 64 + g * 16 + lr) * 8 + e] = f2bf(w3[idx]);
        }
    }

    const float* xb = x + (size_t)b * CC * NN;
    float v[CC];
    float s = 0.f;
    double s64 = 0.0;
#pragma unroll
    for (int c = 0; c < CC; c++) {
        v[c] = xb[(size_t)c * NN + n];
        s = fmaf(v[c], v[c], s);
        s64 += (double)v[c] * (double)v[c];
    }
    float4* dst = (float4*)(xt + ((size_t)b * NN + n) * CC);
#pragma unroll
    for (int q = 0; q < 16; q++) {
        dst[q] = make_float4(v[4 * q], v[4 * q + 1], v[4 * q + 2], v[4 * q + 3]);
    }
    xx64[b * NN + n] = s64;
    u16* dp = xpk + ((size_t)b * NN + n) * RSTRIDE;
#pragma unroll
    for (int q = 0; q < 8; q++) {
        uint4 u;
        u.x = pk2(v[8 * q], v[8 * q + 1]);
        u.y = pk2(v[8 * q + 2], v[8 * q + 3]);
        u.z = pk2(v[8 * q + 4], v[8 * q + 5]);
        u.w = pk2(v[8 * q + 6], v[8 * q + 7]);
        *(uint4*)(dp + q * 8) = u;
    }
    u16 hi = f2bf(s);
    u16 lo = f2bf(s - bf2f(hi));
    uint4 u8;
    u8.x = (unsigned int)hi | ((unsigned int)lo << 16);
    u8.y = 0x00003F80u;  // [66] = bf16(1.0)  (bias column)
    u8.z = 0; u8.w = 0;
    *(uint4*)(dp + 64) = u8;
    uint4 z = {0, 0, 0, 0};
    *(uint4*)(dp + 72) = z;
}

// K2: swapped-operand MFMA KNN, K=80. acc = dot - xx_j/2 + 128 (>0), so fp32
// bits order as u32. 9-bit j-local index packed into low mantissa bits;
// branchless sorting networks. Top-4 per lane half-stream -> 32 cand/i.
// 1D grid + chunked XCD swizzle: each XCD owns 2 consecutive (part,b) pairs
// so the 16 i-blocks sharing a j-slice hit the same L2.
__global__ __launch_bounds__(256) void k_knn3(const u16* __restrict__ xpk,
                                              u16* __restrict__ cand) {
    int tid = threadIdx.x;
    // bijective chunked swizzle over 1024 blocks (divisible by 8)
    int lin = blockIdx.x;
    int swz = (lin & 7) * 128 + (lin >> 3);
    int ib = swz & 15;          // 0..15
    int part = (swz >> 4) & 3;  // 0..3
    int b = swz >> 6;           // 0..15
    int i0 = ib * 128;
    int j00 = part * JPER;

    // Bb: [buf][sub][chunk 0..9][slot=r32^(c&7)][16B]
    __shared__ u16 Bb[2 * 2 * 10 * 32 * 8];  // 20 KB

    int w = tid >> 6, l = tid & 63;
    int lc = l & 31, lh = l >> 5;
    int hb4 = lh * 4;

    // i-fragments: B[k][n]: n=lane&31=i, k=(lane>>5)*8+e. Slice 4 = consts:
    // k=64,65 -> -0.5 (xx fold), k=66 -> 128.0 (bias), rest 0.
    short8 ifrag[5];
    {
        const u16* ip = xpk + ((size_t)b * NN + i0 + w * 32 + lc) * RSTRIDE + lh * 8;
#pragma unroll
        for (int ks = 0; ks < 4; ks++) ifrag[ks] = *(const short8*)(ip + ks * 16);
        short8 f4 = {0, 0, 0, 0, 0, 0, 0, 0};
        if (lh == 0) {
            f4[0] = (short)0xBF00;  // bf16(-0.5)
            f4[1] = (short)0xBF00;
            f4[2] = (short)0x4300;  // bf16(128.0)
        }
        ifrag[4] = f4;
    }

    u32 v0 = 0, v1 = 0, v2 = 0, v3 = 0;  // sorted desc keys (score|index)

#define CE(a, b) { u32 mx_ = umx(a, b); b = umn(a, b); a = mx_; }

#define STAGE(rr, bf)                                                              \
    {                                                                              \
        int jb = j00 + (rr) * 64;                                                  \
        for (int g = tid; g < 640; g += 256) {                                     \
            int rw = g / 10, c = g - rw * 10;                                      \
            uint4 u = *(const uint4*)(xpk + ((size_t)b * NN + jb + rw) * RSTRIDE + \
                                      c * 8);                                      \
            int sub = rw >> 5, r32 = rw & 31;                                      \
            *(uint4*)((char*)Bb + (bf) * 10240 + sub * 5120 + c * 512 +            \
                      ((r32 ^ (c & 7)) * 16)) = u;                                 \
        }                                                                          \
    }

    STAGE(0, 0);

    for (int r = 0; r < JPER / 64; r++) {
        __syncthreads();  // buf[r&1] ready; prev reads of buf[(r+1)&1] done
        if (r + 1 < JPER / 64) STAGE(r + 1, (r + 1) & 1);

        const char* bufp = (const char*)Bb + (r & 1) * 10240;
        f32x16 acc0, acc1;
#pragma unroll
        for (int e = 0; e < 16; e++) {
            acc0[e] = 0.f;
            acc1[e] = 0.f;
        }
#pragma unroll
        for (int ks = 0; ks < 5; ks++) {
            int c = ks * 2 + lh;
            int boff = c * 512 + ((lc ^ (c & 7)) * 16);
            short8 a0 = *(const short8*)(bufp + boff);
            short8 a1 = *(const short8*)(bufp + 5120 + boff);
            acc0 = __builtin_amdgcn_mfma_f32_32x32x16_bf16(a0, ifrag[ks], acc0, 0, 0, 0);
            acc1 = __builtin_amdgcn_mfma_f32_32x32x16_bf16(a1, ifrag[ks], acc1, 0, 0, 0);
        }
#pragma unroll
        for (int sub = 0; sub < 2; sub++) {
            const f32x16& acc = sub ? acc1 : acc0;
            int jlb = r * 64 + sub * 32 + hb4;  // j-local base (9 bits total)
            u32 kk[16];
#pragma unroll
            for (int rg = 0; rg < 16; rg++) {
                u32 u;
                float f = acc[rg];
                __builtin_memcpy(&u, &f, 4);
                int coff = (rg & 3) + 8 * (rg >> 2);
                kk[rg] = (u & ~0x1FFu) | (u32)(jlb + coff);
            }
            // sort each quad desc (5 CE each)
#pragma unroll
            for (int q = 0; q < 4; q++) {
                int p = q * 4;
                CE(kk[p + 0], kk[p + 2]); CE(kk[p + 1], kk[p + 3]);
                CE(kk[p + 0], kk[p + 1]); CE(kk[p + 2], kk[p + 3]);
                CE(kk[p + 1], kk[p + 2]);
            }
            // top4of8(quad0, quad1) -> kk[0..3]
            kk[0] = umx(kk[0], kk[7]); kk[1] = umx(kk[1], kk[6]);
            kk[2] = umx(kk[2], kk[5]); kk[3] = umx(kk[3], kk[4]);
            CE(kk[0], kk[2]); CE(kk[1], kk[3]); CE(kk[0], kk[1]); CE(kk[2], kk[3]);
            // top4of8(quad2, quad3) -> kk[8..11]
            kk[8] = umx(kk[8], kk[15]); kk[9] = umx(kk[9], kk[14]);
            kk[10] = umx(kk[10], kk[13]); kk[11] = umx(kk[11], kk[12]);
            CE(kk[8], kk[10]); CE(kk[9], kk[11]); CE(kk[8], kk[9]); CE(kk[10], kk[11]);
            // top4of8 -> kk[0..3]
            kk[0] = umx(kk[0], kk[11]); kk[1] = umx(kk[1], kk[10]);
            kk[2] = umx(kk[2], kk[9]); kk[3] = umx(kk[3], kk[8]);
            CE(kk[0], kk[2]); CE(kk[1], kk[3]); CE(kk[0], kk[1]); CE(kk[2], kk[3]);
            // merge with running v (sorted desc)
            v0 = umx(v0, kk[3]); v1 = umx(v1, kk[2]);
            v2 = umx(v2, kk[1]); v3 = umx(v3, kk[0]);
            CE(v0, v2); CE(v1, v3); CE(v0, v1); CE(v2, v3);
        }
    }
#undef STAGE
#undef CE

    size_t cb = ((size_t)b * NN + i0 + w * 32 + lc) * NCAND + part * 8 + lh * 4;
    cand[cb + 0] = (u16)(j00 + (v0 & 0x1FF));
    cand[cb + 1] = (u16)(j00 + (v1 & 0x1FF));
    cand[cb + 2] = (u16)(j00 + (v2 & 0x1FF));
    cand[cb + 3] = (u16)(j00 + (v3 & 0x1FF));
}

// K3: fp64 refine, 16-lane coop, FULLY UNROLLED (R25 best): xx64 pre-staged
// to LDS, all 32 candidate chunk loads issued together, then pure compute.
// XCD swizzle keeps gathers L2-local.
__global__ __launch_bounds__(256) void k_knn_merge(const float* __restrict__ xt,
                                                   const double* __restrict__ xx64,
                                                   const u16* __restrict__ cand,
                                                   int* __restrict__ nidx) {
    __shared__ double sv[16 * 33];
    __shared__ double sxx[16 * 33];
    __shared__ u16 jc[16 * 33];

    int tid = threadIdx.x;
    int g = tid >> 4;   // local point 0..15
    int q = tid & 15;   // chunk lane
    // bijective XCD swizzle (gridDim.x = 2048, divisible by 8)
    int nwg8 = (int)(gridDim.x >> 3);
    int swz = (blockIdx.x & 7) * nwg8 + (blockIdx.x >> 3);
    size_t gp0 = (size_t)swz * 16;          // = b*NN + i0
    size_t bbase = (gp0 >> 11) << 11;       // b*NN

    for (int idx = tid; idx < 16 * 32; idx += 256) {
        int p = idx >> 5, c = idx & 31;
        u16 j = cand[(gp0 + p) * NCAND + c];
        jc[p * 33 + c] = j;
        sxx[p * 33 + c] = xx64[bbase + j];
    }
    __syncthreads();

    float4 a = ((const float4*)(xt + (gp0 + g) * CC))[q];

    // all 32 candidate chunk loads in flight together
    float4 bv[NCAND];
#pragma unroll
    for (int c = 0; c < NCAND; c++) {
        bv[c] = ((const float4*)(xt + (bbase + jc[g * 33 + c]) * CC))[q];
    }

#pragma unroll
    for (int c0 = 0; c0 < NCAND; c0 += 4) {
        double d0 = (double)a.x * bv[c0 + 0].x + (double)a.y * bv[c0 + 0].y +
                    (double)a.z * bv[c0 + 0].z + (double)a.w * bv[c0 + 0].w;
        double d1 = (double)a.x * bv[c0 + 1].x + (double)a.y * bv[c0 + 1].y +
                    (double)a.z * bv[c0 + 1].z + (double)a.w * bv[c0 + 1].w;
        double d2 = (double)a.x * bv[c0 + 2].x + (double)a.y * bv[c0 + 2].y +
                    (double)a.z * bv[c0 + 2].z + (double)a.w * bv[c0 + 2].w;
        double d3 = (double)a.x * bv[c0 + 3].x + (double)a.y * bv[c0 + 3].y +
                    (double)a.z * bv[c0 + 3].z + (double)a.w * bv[c0 + 3].w;
        d0 += __shfl_xor(d0, 8); d1 += __shfl_xor(d1, 8);
        d2 += __shfl_xor(d2, 8); d3 += __shfl_xor(d3, 8);
        d0 += __shfl_xor(d0, 4); d1 += __shfl_xor(d1, 4);
        d2 += __shfl_xor(d2, 4); d3 += __shfl_xor(d3, 4);
        d0 += __shfl_xor(d0, 2); d1 += __shfl_xor(d1, 2);
        d2 += __shfl_xor(d2, 2); d3 += __shfl_xor(d3, 2);
        d0 += __shfl_xor(d0, 1); d1 += __shfl_xor(d1, 1);
        d2 += __shfl_xor(d2, 1); d3 += __shfl_xor(d3, 1);
        if (q == 0) {
            sv[g * 33 + c0 + 0] = 2.0 * d0 - sxx[g * 33 + c0 + 0];
            sv[g * 33 + c0 + 1] = 2.0 * d1 - sxx[g * 33 + c0 + 1];
            sv[g * 33 + c0 + 2] = 2.0 * d2 - sxx[g * 33 + c0 + 2];
            sv[g * 33 + c0 + 3] = 2.0 * d3 - sxx[g * 33 + c0 + 3];
        }
    }
    __syncthreads();

    if (tid < 16) {
        int p = tid;
        double v4[4];
        int id4[4];
#pragma unroll
        for (int s = 0; s < 4; s++) {
            v4[s] = -1e300;
            id4[s] = 0x7fffffff;
        }
        for (int cc = 0; cc < NCAND; cc++) {
            double cv = sv[p * 33 + cc];
            int ci = jc[p * 33 + cc];
#pragma unroll
            for (int s = 0; s < 4; s++) {
                bool take = (cv > v4[s]) || (cv == v4[s] && ci < id4[s]);
                double nv = take ? cv : v4[s];
                int ni = take ? ci : id4[s];
                double ov = take ? v4[s] : cv;
                int oi = take ? id4[s] : ci;
                v4[s] = nv;
                id4[s] = ni;
                cv = ov;
                ci = oi;
            }
        }
        size_t gp2 = gp0 + p;
#pragma unroll
        for (int s = 0; s < 4; s++) nidx[gp2 * 4 + s] = id4[s];
    }
}

// K4: fused MFMA MLP. Wave w owns a CHANNEL slice: loads only its own
// weight frags (18 vs 80) and loops the 4 item groups.
__global__ __launch_bounds__(256) void k_mlp(const u16* __restrict__ xpk,
                                             const int* __restrict__ nidx,
                                             const u16* __restrict__ wb1,
                                             const u16* __restrict__ wb2,
                                             const u16* __restrict__ wb3,
                                             const float* __restrict__ b1,
                                             const float* __restrict__ b2,
                                             const float* __restrict__ b3,
                                             float* __restrict__ out) {
    int nch = blockIdx.x;  // 0..127
    int b = blockIdx.y;
    int n0 = nch * 16;
    int tid = threadIdx.x;

    __shared__ u16 Fb[64 * 128];   // raw features bf16, swizzled (16 KB)
    __shared__ u16 E1b[64 * 64];   // relu(e1) (8 KB)
    __shared__ u16 E2b[64 * 128];  // relu(e2) (16 KB)
    __shared__ float Ob[64 * 36];  // e3 k-maxed, padded (9 KB)
    __shared__ int ji[64];

    if (tid < 64) ji[tid] = nidx[((size_t)b * NN + n0) * KK + tid];
    __syncthreads();

    // gather: F[item][0..63]=center, [64..127]=neighbor (swizzled bf16 copy)
    for (int g = tid; g < 64 * 16; g += 256) {
        int it = g >> 4, q = g & 15;
        int half = q >> 3, cq = q & 7;
        int srcn = half ? ji[it] : (n0 + (it >> 2));
        uint4 u = *(const uint4*)(xpk + ((size_t)b * NN + srcn) * RSTRIDE + cq * 8);
        int byte = (it * 256 + half * 128 + cq * 16) ^ ((it & 7) << 4);
        *(uint4*)((char*)Fb + byte) = u;
    }
    __syncthreads();

    int w = tid >> 6, l = tid & 63;
    int lr = l & 15, lg = l >> 4;

    // ---- e1: wave w computes channels w*16..w*16+15 for ALL 64 items ----
    {
        f32x4 acc[4];
#pragma unroll
        for (int g = 0; g < 4; g++) acc[g] = (f32x4){0.f, 0.f, 0.f, 0.f};
#pragma unroll
        for (int ks = 0; ks < 4; ks++) {
            short8 bw = *(const short8*)(wb1 + ((size_t)(w * 4 + ks) * 64 + l) * 8);
#pragma unroll
            for (int g = 0; g < 4; g++) {
                int arow = g * 16 + lr;
                int off = (arow * 256 + ks * 64 + lg * 16) ^ ((arow & 7) << 4);
                short8 a = *(const short8*)((const char*)Fb + off);
                acc[g] = __builtin_amdgcn_mfma_f32_16x16x32_bf16(a, bw, acc[g], 0, 0, 0);
            }
        }
        float bias = b1[w * 16 + lr];
#pragma unroll
        for (int g = 0; g < 4; g++) {
#pragma unroll
            for (int q = 0; q < 4; q++) {
                int item = g * 16 + lg * 4 + q;
                float vv = fmaxf(acc[g][q] + bias, 0.f);
                int byte = (item * 128 + (w * 16 + lr) * 2) ^ ((item & 7) << 4);
                *(u16*)((char*)E1b + byte) = f2bf(vv);
            }
        }
    }
    __syncthreads();

    // ---- e2: wave w computes channels (w*2..w*2+1)*16 for all items ----
    {
        f32x4 acc[4][2];
#pragma unroll
        for (int g = 0; g < 4; g++)
#pragma unroll
            for (int c2 = 0; c2 < 2; c2++) acc[g][c2] = (f32x4){0.f, 0.f, 0.f, 0.f};
#pragma unroll
        for (int ks = 0; ks < 6; ks++) {
            short8 bw0 = *(const short8*)(wb2 + ((size_t)((w * 2) * 6 + ks) * 64 + l) * 8);
            short8 bw1 = *(const short8*)(wb2 + ((size_t)((w * 2 + 1) * 6 + ks) * 64 + l) * 8);
#pragma unroll
            for (int g = 0; g < 4; g++) {
                int arow = g * 16 + lr;
                int aswz = (arow & 7) << 4;
                short8 a;
                if (ks < 2) {
                    int off = (arow * 128 + ks * 64 + lg * 16) ^ aswz;
                    a = *(const short8*)((const char*)E1b + off);
                } else {
                    int off = (arow * 256 + (ks - 2) * 64 + lg * 16) ^ aswz;
                    uint4 u = *(const uint4*)((const char*)Fb + off);
                    unsigned int m;
                    m = ((u.x >> 15) & 0x10001u) * 0xFFFFu; u.x &= ~m;
                    m = ((u.y >> 15) & 0x10001u) * 0xFFFFu; u.y &= ~m;
                    m = ((u.z >> 15) & 0x10001u) * 0xFFFFu; u.z &= ~m;
                    m = ((u.w >> 15) & 0x10001u) * 0xFFFFu; u.w &= ~m;
                    __builtin_memcpy(&a, &u, 16);
                }
                acc[g][0] = __builtin_amdgcn_mfma_f32_16x16x32_bf16(a, bw0, acc[g][0], 0, 0, 0);
                acc[g][1] = __builtin_amdgcn_mfma_f32_16x16x32_bf16(a, bw1, acc[g][1], 0, 0, 0);
            }
        }
#pragma unroll
        for (int c2 = 0; c2 < 2; c2++) {
            float bias = b2[(w * 2 + c2) * 16 + lr];
#pragma unroll
            for (int g = 0; g < 4; g++) {
#pragma unroll
                for (int q = 0; q < 4; q++) {
                    int item = g * 16 + lg * 4 + q;
                    float vv = fmaxf(acc[g][c2][q] + bias, 0.f);
                    int byte = (item * 256 + ((w * 2 + c2) * 16 + lr) * 2) ^ ((item & 7) << 4);
                    *(u16*)((char*)E2b + byte) = f2bf(vv);
                }
            }
        }
    }
    __syncthreads();

    // ---- e3: wave w computes channels w*16..+15; k-max in-lane ----
    {
        f32x4 acc[4][2];
#pragma unroll
        for (int g = 0; g < 4; g++)
#pragma unroll
            for (int r = 0; r < 2; r++) acc[g][r] = (f32x4){0.f, 0.f, 0.f, 0.f};
#pragma unroll
        for (int ks = 0; ks < 2; ks++) {
            short8 bw = *(const short8*)(wb3 + ((size_t)(w * 2 + ks) * 64 + l) * 8);
#pragma unroll
            for (int g = 0; g < 4; g++) {
                int arow = g * 16 + lr;
                int aswz = (arow & 7) << 4;
#pragma unroll
                for (int r = 0; r < 2; r++) {
                    int off = (arow * 256 + r * 128 + ks * 64 + lg * 16) ^ aswz;
                    short8 a = *(const short8*)((const char*)E2b + off);
                    acc[g][r] = __builtin_amdgcn_mfma_f32_16x16x32_bf16(a, bw, acc[g][r], 0, 0, 0);
                }
            }
        }
        float bias = b3[w * 16 + lr];
        int o = w * 16 + lr;
#pragma unroll
        for (int g = 0; g < 4; g++) {
            int nl = g * 4 + lg;
#pragma unroll
            for (int r = 0; r < 2; r++) {
                float m = fmaxf(fmaxf(acc[g][r][0], acc[g][r][1]),
                                fmaxf(acc[g][r][2], acc[g][r][3])) + bias;
                Ob[o * 36 + nl * 2 + r] = m;
            }
        }
    }
    __syncthreads();

    // coalesced store: thread t -> out channel t>>2, 8 floats
    {
        int o = tid >> 2, q = tid & 3;
        float4 v0 = *(const float4*)&Ob[o * 36 + q * 8];
        float4 v1 = *(const float4*)&Ob[o * 36 + q * 8 + 4];
        float* dst = out + ((size_t)(b * 64 + o)) * 4096 + n0 * 2 + q * 8;
        ((float4*)dst)[0] = v0;
        ((float4*)dst)[1] = v1;
    }
}

extern "C" void kernel_launch(void* const* d_in, const int* in_sizes, int n_in,
                              void* d_out, int out_size, void* d_ws, size_t ws_size,
                              hipStream_t stream) {
    const float* x = (const float*)d_in[0];
    const float* w1 = (const float*)d_in[1];
    const float* b1 = (const float*)d_in[2];
    const float* w2 = (const float*)d_in[3];
    const float* b2 = (const float*)d_in[4];
    const float* w3 = (const float*)d_in[5];
    const float* b3 = (const float*)d_in[6];
    float* out = (float*)d_out;

    // workspace layout (~16.1 MB)
    float* xt = (float*)d_ws;                          // B*N*C fp32 = 8 MB
    u16* xpk = (u16*)(xt + (size_t)BB * NN * CC);      // B*N*80 bf16 = 5.24 MB
    double* xx64 = (double*)(xpk + (size_t)BB * NN * RSTRIDE);  // B*N fp64 = 262 KB
    int* nidx = (int*)(xx64 + (size_t)BB * NN);        // B*N*K = 0.5 MB
    u16* cand = (u16*)(nidx + (size_t)BB * NN * KK);   // B*N*32 u16 = 2 MB
    u16* wb1 = cand + (size_t)BB * NN * NCAND;
    u16* wb2 = wb1 + 64 * 128;
    u16* wb3 = wb2 + 128 * 192;

    k_prep<<<dim3(NN / 256, BB), 256, 0, stream>>>(x, xt, xx64, xpk,
                                                   w1, w2, w3, wb1, wb2, wb3);
    k_knn3<<<dim3(NN / 128 * NPART * BB), 256, 0, stream>>>(xpk, cand);
    k_knn_merge<<<dim3(BB * NN / 16), 256, 0, stream>>>(xt, xx64, cand, nidx);
    k_mlp<<<dim3(NN / 16, BB), 256, 0, stream>>>(xpk, nidx, wb1, wb2, wb3, b1, b2, b3, out);
}